// Round 5
// baseline (32.920 us; speedup 1.0000x reference)
//
#include <hip/hip_runtime.h>

// Sequential implicit-midpoint solve, one wave per batch element.
// y_k = y_{k-1} + DT*f_k - DT*tanh(W*(y_k+y_{k-1})/2), NFP=1 fixed-point
// iteration warm-started by the previous step's converged tanh (R4-proven).
//
// R5 change: matvec broadcast via LDS instead of 64x v_readlane.
//   - lane p writes s_p (ds_write_b32), then all lanes read the full vector
//     back as 16x ds_read_b128 (same-address broadcast, conflict-free).
//   - single wave per block => no barrier; the in-order DS pipe orders the
//     write before the reads.
//   - 32x v_pk_fma_f32 on pre-paired W registers halves the FMA count.
// forces prefetched 2 steps deep (step time ~450 cyc < HBM latency).

#define SDIM 64
#define DT_C 0.05f
#define WSCALE 2.8853900817779268f  // 2*log2(e): folds tanh 2x + exp2 conv into W

typedef float v2f __attribute__((ext_vector_type(2)));

__device__ __forceinline__ float recip_fast(float x) {
    float r;
    asm("v_rcp_f32 %0, %1" : "=v"(r) : "v"(x));
    return r;
}

__device__ __forceinline__ float exp2_fast(float x) {
    float r;
    asm("v_exp_f32 %0, %1" : "=v"(r) : "v"(x));
    return r;
}

// u_p = sum_j w[j]*s_j. s distributed one component per lane; sb is a 64-float
// LDS scratch. Returns the dot for this lane's row (w = scaled W row p).
__device__ __forceinline__ float matvec_lds(float* sb, const v2f* w, int p, float s)
{
    sb[p] = s;
    const float4* s4 = reinterpret_cast<const float4*>(sb);
    v2f a0 = {0.f, 0.f}, a1 = {0.f, 0.f}, a2 = {0.f, 0.f}, a3 = {0.f, 0.f};
    #pragma unroll
    for (int i = 0; i < 16; i += 4) {
        float4 q0 = s4[i + 0], q1 = s4[i + 1], q2 = s4[i + 2], q3 = s4[i + 3];
        v2f p00 = {q0.x, q0.y}, p01 = {q0.z, q0.w};
        v2f p10 = {q1.x, q1.y}, p11 = {q1.z, q1.w};
        v2f p20 = {q2.x, q2.y}, p21 = {q2.z, q2.w};
        v2f p30 = {q3.x, q3.y}, p31 = {q3.z, q3.w};
        asm("v_pk_fma_f32 %0, %1, %2, %0" : "+v"(a0) : "v"(w[2*i + 0]), "v"(p00));
        asm("v_pk_fma_f32 %0, %1, %2, %0" : "+v"(a1) : "v"(w[2*i + 1]), "v"(p01));
        asm("v_pk_fma_f32 %0, %1, %2, %0" : "+v"(a2) : "v"(w[2*i + 2]), "v"(p10));
        asm("v_pk_fma_f32 %0, %1, %2, %0" : "+v"(a3) : "v"(w[2*i + 3]), "v"(p11));
        asm("v_pk_fma_f32 %0, %1, %2, %0" : "+v"(a0) : "v"(w[2*i + 4]), "v"(p20));
        asm("v_pk_fma_f32 %0, %1, %2, %0" : "+v"(a1) : "v"(w[2*i + 5]), "v"(p21));
        asm("v_pk_fma_f32 %0, %1, %2, %0" : "+v"(a2) : "v"(w[2*i + 6]), "v"(p30));
        asm("v_pk_fma_f32 %0, %1, %2, %0" : "+v"(a3) : "v"(w[2*i + 7]), "v"(p31));
    }
    v2f aa = (a0 + a1) + (a2 + a3);
    return aa.x + aa.y;
}

__global__ __launch_bounds__(64) void rnes_seq_kernel(
    const float* __restrict__ y0,
    const float* __restrict__ forces,
    const float* __restrict__ W,
    float* __restrict__ out,
    int n, int B)
{
    const int b = blockIdx.x;
    const int p = threadIdx.x;  // lane = state component

    // W row p -> 32 packed f32 pairs, pre-scaled by 2*log2(e)
    v2f w[SDIM / 2];
    {
        const float4* Wrow = reinterpret_cast<const float4*>(W + p * SDIM);
        #pragma unroll
        for (int j4 = 0; j4 < SDIM / 4; ++j4) {
            float4 v = Wrow[j4];
            w[2*j4 + 0] = (v2f){WSCALE * v.x, WSCALE * v.y};
            w[2*j4 + 1] = (v2f){WSCALE * v.z, WSCALE * v.w};
        }
    }

    __shared__ __align__(16) float sb[SDIM];

    const size_t stride = (size_t)B * SDIM;
    const int off = b * SDIM + p;

    float yprev = y0[off];
    out[off] = yprev;  // out[0] = y0 pass-through

    // Seed tanh carry at s ~= y0
    float tcar;
    {
        const float u = matvec_lds(sb, w, p, yprev);
        tcar = fmaf(-2.0f, recip_fast(exp2_fast(u) + 1.0f), 1.0f);
    }

    // 2-deep force prefetch ring (step time < HBM latency)
    float fA = forces[stride + off];                        // f_1
    float fB = (n > 2) ? forces[2 * stride + off] : 0.f;    // f_2
    const float* fpre = forces + 3 * stride + off;          // next: f_3
    float* op = out + stride + off;

    #pragma unroll 1
    for (int k = 1; k < n; ++k) {
        float fC = 0.f;
        if (k + 2 < n) fC = *fpre;   // prefetch f_{k+2}
        fpre += stride;

        const float c0 = fmaf(DT_C, fA, yprev);                  // yprev + DT*f
        const float s  = fmaf(0.5f * DT_C, fA - tcar, yprev);    // 0.5*(y_pred+yprev)
        const float u  = matvec_lds(sb, w, p, s);
        const float r  = recip_fast(exp2_fast(u) + 1.0f);        // 1/(e^{2Ws}+1)
        const float y  = fmaf(2.0f * DT_C, r, c0 - DT_C);        // c0 - DT*tanh

        *op = y;
        op += stride;
        yprev = y;
        tcar = fmaf(-2.0f, r, 1.0f);  // tanh carry for next predictor
        fA = fB;
        fB = fC;
    }
}

extern "C" void kernel_launch(void* const* d_in, const int* in_sizes, int n_in,
                              void* d_out, int out_size, void* d_ws, size_t ws_size,
                              hipStream_t stream) {
    const float* y0     = (const float*)d_in[0];   // (B, S)
    const float* forces = (const float*)d_in[1];   // (n, B, S)
    const float* W      = (const float*)d_in[2];   // (S, S)
    float* out = (float*)d_out;                    // (n, B, S)

    const int BS = in_sizes[0];       // B * S
    const int B  = BS / SDIM;         // 128
    const int n  = in_sizes[1] / BS;  // 65

    rnes_seq_kernel<<<B, SDIM, 0, stream>>>(y0, forces, W, out, n, B);
}

// Round 7
// 25.056 us; speedup vs baseline: 1.3138x; 1.3138x over previous
//
#include <hip/hip_runtime.h>

// Sequential implicit-midpoint solve, one wave per batch element.
// y_k = y_{k-1} + DT*f_k - DT*tanh(W*(y_k+y_{k-1})/2), NFP=1 fixed-point
// iteration warm-started by the previous step's converged tanh (R4-proven).
//
// R6/R7: matvec via f16 packed dot products (official builtin semantics):
//   - even lane 2m packs (s[2m], s[2m+1]) as half2: DPP quad_perm [1,0,3,2]
//     neighbor fetch + v_cvt_pkrtz_f16_f32.
//   - 32x v_readlane (packed pair -> SGPR) + 32x __builtin_amdgcn_fdot2
//     (v_dot2_f32_f16, f32 accumulate), 8 accumulator chains.
// Halves both the readlane count (64->32, ~12 cyc each: SGPR-write hazard)
// and the FMA count (64->32) vs R4. No LDS on the critical path (R5 showed
// LDS round-trips are wait-bound for a solo wave).
// W pre-scaled by 2*log2(e) BEFORE f16 pack so tanh = 1 - 2/(exp2(u)+1).
// R7 fix: union-bitcast between __fp16x2 (cvt_pkrtz return) and _Float16x2
// (fdot2 operand) — bit-identical, clang just treats them as distinct types.

#define SDIM 64
#define DT_C 0.05f
#define WSCALE 2.8853900817779268f  // 2*log2(e)

typedef _Float16 h2 __attribute__((ext_vector_type(2)));  // fdot2 operand type
typedef __fp16   g2 __attribute__((ext_vector_type(2)));  // cvt_pkrtz return type
union H2U { int i; h2 h; g2 g; };

__device__ __forceinline__ float recip_fast(float x) {
    float r;
    asm("v_rcp_f32 %0, %1" : "=v"(r) : "v"(x));
    return r;
}

__device__ __forceinline__ float exp2_fast(float x) {
    float r;
    asm("v_exp_f32 %0, %1" : "=v"(r) : "v"(x));
    return r;
}

__device__ __forceinline__ h2 pack_h2(float a, float b) {
    H2U u; u.g = __builtin_amdgcn_cvt_pkrtz(a, b); return u.h;
}
__device__ __forceinline__ h2 int_as_h2(int v) {
    H2U u; u.i = v; return u.h;
}
__device__ __forceinline__ int h2_as_int(h2 v) {
    H2U u; u.h = v; return u.i;
}

// u_p = sum_j w[j]*s_j ; s distributed one component per lane, wp = packed
// (scaled) W row p as 32 half2. Returns this lane's row dot.
__device__ __forceinline__ float wave_matvec_f16(const h2* __restrict__ wp, float s)
{
    // neighbor s via DPP quad_perm [1,0,3,2] (0xB1); even lane 2m: s[2m+1]
    const int sb = __float_as_int(s);
    const int nb = __builtin_amdgcn_update_dpp(0, sb, 0xB1, 0xF, 0xF, true);
    const int pki = h2_as_int(pack_h2(s, __int_as_float(nb)));

    float a0 = 0.f, a1 = 0.f, a2 = 0.f, a3 = 0.f;
    float a4 = 0.f, a5 = 0.f, a6 = 0.f, a7 = 0.f;
    #pragma unroll
    for (int m = 0; m < 32; m += 8) {
        const int b0 = __builtin_amdgcn_readlane(pki, 2 * (m + 0));
        const int b1 = __builtin_amdgcn_readlane(pki, 2 * (m + 1));
        const int b2 = __builtin_amdgcn_readlane(pki, 2 * (m + 2));
        const int b3 = __builtin_amdgcn_readlane(pki, 2 * (m + 3));
        const int b4 = __builtin_amdgcn_readlane(pki, 2 * (m + 4));
        const int b5 = __builtin_amdgcn_readlane(pki, 2 * (m + 5));
        const int b6 = __builtin_amdgcn_readlane(pki, 2 * (m + 6));
        const int b7 = __builtin_amdgcn_readlane(pki, 2 * (m + 7));
        a0 = __builtin_amdgcn_fdot2(wp[m + 0], int_as_h2(b0), a0, false);
        a1 = __builtin_amdgcn_fdot2(wp[m + 1], int_as_h2(b1), a1, false);
        a2 = __builtin_amdgcn_fdot2(wp[m + 2], int_as_h2(b2), a2, false);
        a3 = __builtin_amdgcn_fdot2(wp[m + 3], int_as_h2(b3), a3, false);
        a4 = __builtin_amdgcn_fdot2(wp[m + 4], int_as_h2(b4), a4, false);
        a5 = __builtin_amdgcn_fdot2(wp[m + 5], int_as_h2(b5), a5, false);
        a6 = __builtin_amdgcn_fdot2(wp[m + 6], int_as_h2(b6), a6, false);
        a7 = __builtin_amdgcn_fdot2(wp[m + 7], int_as_h2(b7), a7, false);
    }
    return (((a0 + a1) + (a2 + a3)) + ((a4 + a5) + (a6 + a7)));
}

__global__ __launch_bounds__(64) void rnes_seq_kernel(
    const float* __restrict__ y0,
    const float* __restrict__ forces,
    const float* __restrict__ W,
    float* __restrict__ out,
    int n, int B)
{
    const int b = blockIdx.x;
    const int p = threadIdx.x;  // lane = state component

    // W row p -> 32 half2, pre-scaled by 2*log2(e)
    h2 wp[SDIM / 2];
    {
        const float4* Wrow = reinterpret_cast<const float4*>(W + p * SDIM);
        #pragma unroll
        for (int j4 = 0; j4 < SDIM / 4; ++j4) {
            float4 v = Wrow[j4];
            wp[2 * j4 + 0] = pack_h2(WSCALE * v.x, WSCALE * v.y);
            wp[2 * j4 + 1] = pack_h2(WSCALE * v.z, WSCALE * v.w);
        }
    }

    const size_t stride = (size_t)B * SDIM;
    const int off = b * SDIM + p;

    float yprev = y0[off];
    out[off] = yprev;  // out[0] = y0 pass-through

    // Seed tanh carry at s ~= y0
    float tcar;
    {
        const float u = wave_matvec_f16(wp, yprev);
        tcar = fmaf(-2.0f, recip_fast(exp2_fast(u) + 1.0f), 1.0f);
    }

    // 2-deep force prefetch ring (step time < HBM latency)
    float fA = forces[stride + off];                      // f_1
    float fB = (n > 2) ? forces[2 * stride + off] : 0.f;  // f_2
    const float* fpre = forces + 3 * stride + off;        // next: f_3
    float* op = out + stride + off;

    #pragma unroll 1
    for (int k = 1; k < n; ++k) {
        float fC = 0.f;
        if (k + 2 < n) fC = *fpre;  // prefetch f_{k+2}, two steps of slack
        fpre += stride;

        const float c0 = fmaf(DT_C, fA, yprev);               // yprev + DT*f
        const float s  = fmaf(0.5f * DT_C, fA - tcar, yprev); // 0.5*(y_pred+yprev)
        const float u  = wave_matvec_f16(wp, s);
        const float r  = recip_fast(exp2_fast(u) + 1.0f);     // 1/(e^{2Ws}+1)
        const float y  = fmaf(2.0f * DT_C, r, c0 - DT_C);     // c0 - DT*tanh

        *op = y;
        op += stride;
        yprev = y;
        tcar = fmaf(-2.0f, r, 1.0f);  // tanh carry for next predictor
        fA = fB;
        fB = fC;
    }
}

extern "C" void kernel_launch(void* const* d_in, const int* in_sizes, int n_in,
                              void* d_out, int out_size, void* d_ws, size_t ws_size,
                              hipStream_t stream) {
    const float* y0     = (const float*)d_in[0];   // (B, S)
    const float* forces = (const float*)d_in[1];   // (n, B, S)
    const float* W      = (const float*)d_in[2];   // (S, S)
    float* out = (float*)d_out;                    // (n, B, S)

    const int BS = in_sizes[0];       // B * S
    const int B  = BS / SDIM;         // 128
    const int n  = in_sizes[1] / BS;  // 65

    rnes_seq_kernel<<<B, SDIM, 0, stream>>>(y0, forces, W, out, n, B);
}

// Round 8
// 21.541 us; speedup vs baseline: 1.5282x; 1.1632x over previous
//
#include <hip/hip_runtime.h>

// Sequential implicit-midpoint solve, one wave per batch element.
// y_k = y_{k-1} + DT*f_k - DT*tanh(W*(y_k+y_{k-1})/2).
//
// R8: 2-step speculative pipeline. Per pair-iteration, TWO matvec chains run
// interleaved:
//   chain A (exact, R7 scheme):  s_k   = yprev + 0.5*DT*(f_k - tcar)
//   chain B (speculative):       s_k+1 = y_pred_k + 0.5*DT*(f_k+1 - tcar)
// tcar = tanh carried from the previous pair (1-step stale for A, 2-step for
// B). Speculation error enters ONLY the tanh argument (the c0 recurrence uses
// corrected y), so it doesn't compound: ~1e-4/step, <=6e-3 accumulated.
// The interleaved chains fill each other's readlane->SGPR->fdot2 hazard
// slots (R7 measured ~450 cyc/step of pure stall).
//
// Matvec: f16 packed pairs, 32x v_readlane + 32x v_dot2_f32_f16 per chain
// (R7-proven). W pre-scaled by 2*log2(e): tanh = 1 - 2/(exp2(u)+1).

#define SDIM 64
#define DT_C 0.05f
#define WSCALE 2.8853900817779268f  // 2*log2(e)

typedef _Float16 h2 __attribute__((ext_vector_type(2)));  // fdot2 operand type
typedef __fp16   g2 __attribute__((ext_vector_type(2)));  // cvt_pkrtz return type
union H2U { int i; h2 h; g2 g; };

__device__ __forceinline__ float recip_fast(float x) {
    float r;
    asm("v_rcp_f32 %0, %1" : "=v"(r) : "v"(x));
    return r;
}

__device__ __forceinline__ float exp2_fast(float x) {
    float r;
    asm("v_exp_f32 %0, %1" : "=v"(r) : "v"(x));
    return r;
}

__device__ __forceinline__ h2 pack_h2(float a, float b) {
    H2U u; u.g = __builtin_amdgcn_cvt_pkrtz(a, b); return u.h;
}
__device__ __forceinline__ h2 int_as_h2(int v) {
    H2U u; u.i = v; return u.h;
}
__device__ __forceinline__ int h2_as_int(h2 v) {
    H2U u; u.h = v; return u.i;
}

// Two interleaved row-dots: uA = (W sA)_p, uB = (W sB)_p. s* distributed one
// component per lane; wp = packed (scaled) W row p as 32 half2.
__device__ __forceinline__ void wave_matvec2_f16(const h2* __restrict__ wp,
                                                 float sA, float sB,
                                                 float& uA, float& uB)
{
    // neighbor via DPP quad_perm [1,0,3,2]; even lane 2m packs (s[2m], s[2m+1])
    const int sbA = __float_as_int(sA);
    const int nbA = __builtin_amdgcn_update_dpp(0, sbA, 0xB1, 0xF, 0xF, true);
    const int pkA = h2_as_int(pack_h2(sA, __int_as_float(nbA)));
    const int sbB = __float_as_int(sB);
    const int nbB = __builtin_amdgcn_update_dpp(0, sbB, 0xB1, 0xF, 0xF, true);
    const int pkB = h2_as_int(pack_h2(sB, __int_as_float(nbB)));

    float aA0 = 0.f, aA1 = 0.f, aA2 = 0.f, aA3 = 0.f;
    float aB0 = 0.f, aB1 = 0.f, aB2 = 0.f, aB3 = 0.f;
    #pragma unroll
    for (int m = 0; m < 32; m += 4) {
        const int a0 = __builtin_amdgcn_readlane(pkA, 2 * (m + 0));
        const int a1 = __builtin_amdgcn_readlane(pkA, 2 * (m + 1));
        const int a2 = __builtin_amdgcn_readlane(pkA, 2 * (m + 2));
        const int a3 = __builtin_amdgcn_readlane(pkA, 2 * (m + 3));
        const int b0 = __builtin_amdgcn_readlane(pkB, 2 * (m + 0));
        const int b1 = __builtin_amdgcn_readlane(pkB, 2 * (m + 1));
        const int b2 = __builtin_amdgcn_readlane(pkB, 2 * (m + 2));
        const int b3 = __builtin_amdgcn_readlane(pkB, 2 * (m + 3));
        aA0 = __builtin_amdgcn_fdot2(wp[m + 0], int_as_h2(a0), aA0, false);
        aA1 = __builtin_amdgcn_fdot2(wp[m + 1], int_as_h2(a1), aA1, false);
        aA2 = __builtin_amdgcn_fdot2(wp[m + 2], int_as_h2(a2), aA2, false);
        aA3 = __builtin_amdgcn_fdot2(wp[m + 3], int_as_h2(a3), aA3, false);
        aB0 = __builtin_amdgcn_fdot2(wp[m + 0], int_as_h2(b0), aB0, false);
        aB1 = __builtin_amdgcn_fdot2(wp[m + 1], int_as_h2(b1), aB1, false);
        aB2 = __builtin_amdgcn_fdot2(wp[m + 2], int_as_h2(b2), aB2, false);
        aB3 = __builtin_amdgcn_fdot2(wp[m + 3], int_as_h2(b3), aB3, false);
    }
    uA = (aA0 + aA1) + (aA2 + aA3);
    uB = (aB0 + aB1) + (aB2 + aB3);
}

__global__ __launch_bounds__(64) void rnes_seq_kernel(
    const float* __restrict__ y0,
    const float* __restrict__ forces,
    const float* __restrict__ W,
    float* __restrict__ out,
    int n, int B)
{
    const int b = blockIdx.x;
    const int p = threadIdx.x;  // lane = state component

    // W row p -> 32 half2, pre-scaled by 2*log2(e)
    h2 wp[SDIM / 2];
    {
        const float4* Wrow = reinterpret_cast<const float4*>(W + p * SDIM);
        #pragma unroll
        for (int j4 = 0; j4 < SDIM / 4; ++j4) {
            float4 v = Wrow[j4];
            wp[2 * j4 + 0] = pack_h2(WSCALE * v.x, WSCALE * v.y);
            wp[2 * j4 + 1] = pack_h2(WSCALE * v.z, WSCALE * v.w);
        }
    }

    const size_t stride = (size_t)B * SDIM;
    const int off = b * SDIM + p;

    float yprev = y0[off];
    out[off] = yprev;  // out[0] = y0 pass-through

    // Seed tanh carry at s ~= y0
    float uA, uB;
    float tcar;
    {
        wave_matvec2_f16(wp, yprev, yprev, uA, uB);
        tcar = fmaf(-2.0f, recip_fast(exp2_fast(uA) + 1.0f), 1.0f);
    }

    // force ring: fA=f_k, fB=f_{k+1}, fC=f_{k+2}, fD=f_{k+3}
    float fA = (n > 1) ? forces[1 * stride + off] : 0.f;
    float fB = (n > 2) ? forces[2 * stride + off] : 0.f;
    float fC = (n > 3) ? forces[3 * stride + off] : 0.f;
    float fD = (n > 4) ? forces[4 * stride + off] : 0.f;
    const float* fpre = forces + 5 * stride + off;  // next to load: f_5
    float* op = out + stride + off;

    int k = 1;
    #pragma unroll 1
    for (; k + 1 < n; k += 2) {
        // prefetch pair (k+4, k+5): two pair-iterations (~1800 cyc) of slack
        float fE = 0.f, fF = 0.f;
        if (k + 4 < n) fE = fpre[0];
        if (k + 5 < n) fF = fpre[stride];
        fpre += 2 * stride;

        const float ypA = fmaf(DT_C, fA - tcar, yprev);          // y_pred_k
        const float sA  = fmaf(0.5f * DT_C, fA - tcar, yprev);   // exact-scheme midpoint
        const float sB  = fmaf(0.5f * DT_C, fB - tcar, ypA);     // speculative midpoint

        wave_matvec2_f16(wp, sA, sB, uA, uB);

        const float rA = recip_fast(exp2_fast(uA) + 1.0f);
        const float rB = recip_fast(exp2_fast(uB) + 1.0f);
        const float yk  = fmaf(2.0f * DT_C, rA, fmaf(DT_C, fA, yprev) - DT_C);
        const float yk1 = fmaf(2.0f * DT_C, rB, fmaf(DT_C, fB, yk) - DT_C);

        op[0]      = yk;
        op[stride] = yk1;
        op += 2 * stride;
        yprev = yk1;
        tcar = fmaf(-2.0f, rB, 1.0f);  // tanh carry (1-step stale for next A)
        fA = fC; fB = fD; fC = fE; fD = fF;
    }

    // odd tail (not hit for n=65, kept for generality)
    if (k < n) {
        const float sA = fmaf(0.5f * DT_C, fA - tcar, yprev);
        wave_matvec2_f16(wp, sA, sA, uA, uB);
        const float rA = recip_fast(exp2_fast(uA) + 1.0f);
        const float yk = fmaf(2.0f * DT_C, rA, fmaf(DT_C, fA, yprev) - DT_C);
        *op = yk;
    }
}

extern "C" void kernel_launch(void* const* d_in, const int* in_sizes, int n_in,
                              void* d_out, int out_size, void* d_ws, size_t ws_size,
                              hipStream_t stream) {
    const float* y0     = (const float*)d_in[0];   // (B, S)
    const float* forces = (const float*)d_in[1];   // (n, B, S)
    const float* W      = (const float*)d_in[2];   // (S, S)
    float* out = (float*)d_out;                    // (n, B, S)

    const int BS = in_sizes[0];       // B * S
    const int B  = BS / SDIM;         // 128
    const int n  = in_sizes[1] / BS;  // 65

    rnes_seq_kernel<<<B, SDIM, 0, stream>>>(y0, forces, W, out, n, B);
}

// Round 10
// 20.766 us; speedup vs baseline: 1.5853x; 1.0373x over previous
//
#include <hip/hip_runtime.h>

// Sequential implicit-midpoint solve, one wave per batch element.
// y_k = y_{k-1} + DT*f_k - DT*tanh(W*(y_k+y_{k-1})/2).
//
// R10 = R9 (2-step speculative pipeline + LDS broadcast matvec) with the
// write->read ordering made airtight:
//   - branchless: even lane 2m writes A-pair (sA[2m],sA[2m+1]) at dword 2m,
//     odd lane 2m+1 writes B-pair swap-packed (sB[2m],sB[2m+1]) at dword
//     2m+1. One ds_write_b32/lane, 2 lanes/bank = free, no divergence.
//   - asm memory clobber (IR fence) + sched_barrier(0) (MIR fence) between
//     the write and the 16 staged broadcast ds_read_b128. R9's failure was
//     the compiler hoisting the TBAA-distinct reads above the write.
// Single wave per block: in-order DS pipe gives RAW at HW level; the fences
// give it at compiler level.
// Matvec consume: 64x v_dot2_f32_f16, 8 accumulator chains (R7/R8-proven).
// W pre-scaled by 2*log2(e): tanh(Ws) = 1 - 2/(exp2(u)+1).

#define SDIM 64
#define DT_C 0.05f
#define WSCALE 2.8853900817779268f  // 2*log2(e)

typedef _Float16 h2 __attribute__((ext_vector_type(2)));  // fdot2 operand type
typedef __fp16   g2 __attribute__((ext_vector_type(2)));  // cvt_pkrtz return type
union H2U { int i; h2 h; g2 g; };

__device__ __forceinline__ float recip_fast(float x) {
    float r;
    asm("v_rcp_f32 %0, %1" : "=v"(r) : "v"(x));
    return r;
}

__device__ __forceinline__ float exp2_fast(float x) {
    float r;
    asm("v_exp_f32 %0, %1" : "=v"(r) : "v"(x));
    return r;
}

__device__ __forceinline__ h2 pack_h2(float a, float b) {
    H2U u; u.g = __builtin_amdgcn_cvt_pkrtz(a, b); return u.h;
}
__device__ __forceinline__ h2 int_as_h2(int v) {
    H2U u; u.i = v; return u.h;
}
__device__ __forceinline__ int h2_as_int(h2 v) {
    H2U u; u.h = v; return u.i;
}

// Two row-dots via LDS broadcast: uA=(W sA)_p, uB=(W sB)_p.
// lds = 64-int shared buffer; wp = packed (scaled) W row p as 32 half2.
__device__ __forceinline__ void wave_matvec2_lds(int* lds,
                                                 const h2* __restrict__ wp,
                                                 int p, float sA, float sB,
                                                 float& uA, float& uB)
{
    // neighbor via DPP quad_perm [1,0,3,2] (0xB1)
    const int sbA = __float_as_int(sA);
    const int nbA = __builtin_amdgcn_update_dpp(0, sbA, 0xB1, 0xF, 0xF, true);
    const int sbB = __float_as_int(sB);
    const int nbB = __builtin_amdgcn_update_dpp(0, sbB, 0xB1, 0xF, 0xF, true);
    // even lane 2m: (sA[2m], sA[2m+1]);  odd lane 2m+1: (sB[2m], sB[2m+1])
    const int pkA  = h2_as_int(pack_h2(sA, __int_as_float(nbA)));
    const int pkBs = h2_as_int(pack_h2(__int_as_float(nbB), sB));

    // interleaved layout: dword 2m = A_m, dword 2m+1 = B_m
    lds[p] = (p & 1) ? pkBs : pkA;

    // ---- ordering fence: write must precede the staged reads ----
    asm volatile("" ::: "memory");
    __builtin_amdgcn_sched_barrier(0);

    // stage ALL 64 dwords as 16 broadcast b128 reads (pipelined in DS pipe)
    const int4* q4 = reinterpret_cast<const int4*>(lds);
    int4 q0 = q4[0],  q1 = q4[1],  q2 = q4[2],  q3 = q4[3];
    int4 q4_ = q4[4], q5 = q4[5],  q6 = q4[6],  q7 = q4[7];
    int4 q8 = q4[8],  q9 = q4[9],  qa = q4[10], qb = q4[11];
    int4 qc = q4[12], qd = q4[13], qe = q4[14], qf = q4[15];

    float aA0 = 0.f, aA1 = 0.f, aA2 = 0.f, aA3 = 0.f;
    float aB0 = 0.f, aB1 = 0.f, aB2 = 0.f, aB3 = 0.f;

    // q_i = (A_{2i}, B_{2i}, A_{2i+1}, B_{2i+1})
#define DOT4(qi, m)                                                           \
    aA0 = __builtin_amdgcn_fdot2(wp[(m)],     int_as_h2((qi).x), aA0, false); \
    aB0 = __builtin_amdgcn_fdot2(wp[(m)],     int_as_h2((qi).y), aB0, false); \
    aA1 = __builtin_amdgcn_fdot2(wp[(m) + 1], int_as_h2((qi).z), aA1, false); \
    aB1 = __builtin_amdgcn_fdot2(wp[(m) + 1], int_as_h2((qi).w), aB1, false)
#define DOT4H(qi, m)                                                          \
    aA2 = __builtin_amdgcn_fdot2(wp[(m)],     int_as_h2((qi).x), aA2, false); \
    aB2 = __builtin_amdgcn_fdot2(wp[(m)],     int_as_h2((qi).y), aB2, false); \
    aA3 = __builtin_amdgcn_fdot2(wp[(m) + 1], int_as_h2((qi).z), aA3, false); \
    aB3 = __builtin_amdgcn_fdot2(wp[(m) + 1], int_as_h2((qi).w), aB3, false)

    DOT4(q0, 0);   DOT4H(q1, 2);   DOT4(q2, 4);   DOT4H(q3, 6);
    DOT4(q4_, 8);  DOT4H(q5, 10);  DOT4(q6, 12);  DOT4H(q7, 14);
    DOT4(q8, 16);  DOT4H(q9, 18);  DOT4(qa, 20);  DOT4H(qb, 22);
    DOT4(qc, 24);  DOT4H(qd, 26);  DOT4(qe, 28);  DOT4H(qf, 30);
#undef DOT4
#undef DOT4H

    uA = (aA0 + aA1) + (aA2 + aA3);
    uB = (aB0 + aB1) + (aB2 + aB3);
}

__global__ __launch_bounds__(64) void rnes_seq_kernel(
    const float* __restrict__ y0,
    const float* __restrict__ forces,
    const float* __restrict__ W,
    float* __restrict__ out,
    int n, int B)
{
    const int b = blockIdx.x;
    const int p = threadIdx.x;  // lane = state component

    // W row p -> 32 half2, pre-scaled by 2*log2(e)
    h2 wp[SDIM / 2];
    {
        const float4* Wrow = reinterpret_cast<const float4*>(W + p * SDIM);
        #pragma unroll
        for (int j4 = 0; j4 < SDIM / 4; ++j4) {
            float4 v = Wrow[j4];
            wp[2 * j4 + 0] = pack_h2(WSCALE * v.x, WSCALE * v.y);
            wp[2 * j4 + 1] = pack_h2(WSCALE * v.z, WSCALE * v.w);
        }
    }

    __shared__ __align__(16) int lds[SDIM];

    const size_t stride = (size_t)B * SDIM;
    const int off = b * SDIM + p;

    float yprev = y0[off];
    out[off] = yprev;  // out[0] = y0 pass-through

    // Seed tanh carry at s ~= y0
    float uA, uB;
    float tcar;
    {
        wave_matvec2_lds(lds, wp, p, yprev, yprev, uA, uB);
        tcar = fmaf(-2.0f, recip_fast(exp2_fast(uA) + 1.0f), 1.0f);
    }

    // force ring: fA=f_k, fB=f_{k+1}, fC=f_{k+2}, fD=f_{k+3}
    float fA = (n > 1) ? forces[1 * stride + off] : 0.f;
    float fB = (n > 2) ? forces[2 * stride + off] : 0.f;
    float fC = (n > 3) ? forces[3 * stride + off] : 0.f;
    float fD = (n > 4) ? forces[4 * stride + off] : 0.f;
    const float* fpre = forces + 5 * stride + off;  // next to load: f_5
    float* op = out + stride + off;

    int k = 1;
    #pragma unroll 1
    for (; k + 1 < n; k += 2) {
        // prefetch pair (k+4, k+5): two pair-iterations of slack
        float fE = 0.f, fF = 0.f;
        if (k + 4 < n) fE = fpre[0];
        if (k + 5 < n) fF = fpre[stride];
        fpre += 2 * stride;

        const float ypA = fmaf(DT_C, fA - tcar, yprev);          // y_pred_k
        const float sA  = fmaf(0.5f * DT_C, fA - tcar, yprev);   // exact midpoint
        const float sB  = fmaf(0.5f * DT_C, fB - tcar, ypA);     // speculative midpoint

        wave_matvec2_lds(lds, wp, p, sA, sB, uA, uB);

        const float rA = recip_fast(exp2_fast(uA) + 1.0f);
        const float rB = recip_fast(exp2_fast(uB) + 1.0f);
        const float yk  = fmaf(2.0f * DT_C, rA, fmaf(DT_C, fA, yprev) - DT_C);
        const float yk1 = fmaf(2.0f * DT_C, rB, fmaf(DT_C, fB, yk) - DT_C);

        op[0]      = yk;
        op[stride] = yk1;
        op += 2 * stride;
        yprev = yk1;
        tcar = fmaf(-2.0f, rB, 1.0f);  // tanh carry (1-step stale for next A)
        fA = fC; fB = fD; fC = fE; fD = fF;
    }

    // odd tail (not hit for n=65, kept for generality)
    if (k < n) {
        const float sA = fmaf(0.5f * DT_C, fA - tcar, yprev);
        wave_matvec2_lds(lds, wp, p, sA, sA, uA, uB);
        const float rA = recip_fast(exp2_fast(uA) + 1.0f);
        const float yk = fmaf(2.0f * DT_C, rA, fmaf(DT_C, fA, yprev) - DT_C);
        *op = yk;
    }
}

extern "C" void kernel_launch(void* const* d_in, const int* in_sizes, int n_in,
                              void* d_out, int out_size, void* d_ws, size_t ws_size,
                              hipStream_t stream) {
    const float* y0     = (const float*)d_in[0];   // (B, S)
    const float* forces = (const float*)d_in[1];   // (n, B, S)
    const float* W      = (const float*)d_in[2];   // (S, S)
    float* out = (float*)d_out;                    // (n, B, S)

    const int BS = in_sizes[0];       // B * S
    const int B  = BS / SDIM;         // 128
    const int n  = in_sizes[1] / BS;  // 65

    rnes_seq_kernel<<<B, SDIM, 0, stream>>>(y0, forces, W, out, n, B);
}